// Round 4
// baseline (436.921 us; speedup 1.0000x reference)
//
#include <hip/hip_runtime.h>
#include <hip/hip_bf16.h>

#define D_DIM 2048
#define F_DIM 1024
#define E_NUM 16
#define T_TOK 2048

typedef float f32x4 __attribute__((ext_vector_type(4)));
typedef short short8 __attribute__((ext_vector_type(8)));

__device__ inline unsigned pk2bf(float a, float b) {
    __hip_bfloat162 h2 = __float22bfloat162_rn(make_float2(a, b));
    union { __hip_bfloat162 h; unsigned u; } c; c.h = h2; return c.u;
}

// ---------------- routing: 1 wave per token ----------------
__global__ __launch_bounds__(64) void k_route(const float* __restrict__ x,
                                              const float* __restrict__ wg,
                                              const float* __restrict__ bias,
                                              int* __restrict__ topk_idx,
                                              float* __restrict__ topk_w,
                                              int* __restrict__ counts) {
    int t = blockIdx.x;
    int l = threadIdx.x;
    int e = l & 15, c = l >> 4;
    const float* xr = x + (size_t)t * D_DIM + c * (D_DIM / 4);
    const float* wr = wg + (size_t)(c * (D_DIM / 4)) * E_NUM + e;
    float acc = 0.f;
#pragma unroll 4
    for (int d = 0; d < D_DIM / 4; ++d) acc += xr[d] * wr[(size_t)d * E_NUM];
    acc += __shfl_xor(acc, 16);
    acc += __shfl_xor(acc, 32);
    float m = acc;
#pragma unroll
    for (int s = 1; s < 16; s <<= 1) m = fmaxf(m, __shfl_xor(m, s));
    float p = __expf(acc - m);
    float sum = p;
#pragma unroll
    for (int s = 1; s < 16; s <<= 1) sum += __shfl_xor(sum, s);
    p = p / sum + bias[e];
    float v1 = p; int i1 = e;
#pragma unroll
    for (int s = 1; s < 16; s <<= 1) {
        float ov = __shfl_xor(v1, s); int oi = __shfl_xor(i1, s);
        if (ov > v1 || (ov == v1 && oi < i1)) { v1 = ov; i1 = oi; }
    }
    float v2 = (e == i1) ? -1e30f : p; int i2 = e;
#pragma unroll
    for (int s = 1; s < 16; s <<= 1) {
        float ov = __shfl_xor(v2, s); int oi = __shfl_xor(i2, s);
        if (ov > v2 || (ov == v2 && oi < i2)) { v2 = ov; i2 = oi; }
    }
    if (l == 0) {
        float s2 = v1 + v2 + 1e-20f;
        topk_idx[2 * t] = i1; topk_idx[2 * t + 1] = i2;
        topk_w[2 * t] = v1 / s2; topk_w[2 * t + 1] = v2 / s2;
        atomicAdd(&counts[i1], 1);
        atomicAdd(&counts[i2], 1);
    }
}

__global__ void k_offsets(const int* __restrict__ counts, int* __restrict__ offsets,
                          int* __restrict__ cursors) {
    if (threadIdx.x == 0) {
        int run = 0;
        for (int e = 0; e < E_NUM; ++e) { offsets[e] = run; cursors[e] = run; run += counts[e]; }
        offsets[E_NUM] = run;
    }
}

__global__ void k_scatter(const int* __restrict__ topk_idx, const float* __restrict__ topk_w,
                          int* __restrict__ cursors, int* __restrict__ token_ids,
                          float* __restrict__ slot_w) {
    int i = blockIdx.x * blockDim.x + threadIdx.x;
    if (i >= T_TOK * 2) return;
    int e = topk_idx[i];
    int slot = atomicAdd(&cursors[e], 1);
    token_ids[slot] = i >> 1;
    slot_w[slot] = topk_w[i];
}

// ================= gate+up grouped GEMM =================
// tile 128(slots) x 64(F), BK=32, 4 waves (2x2), double-buffered.
// A LDS: [128 rows][32 k] bf16, stride 40 shorts.  B LDS: K-major [64 cols][32 k], stride 40.
// B staging: thread owns 1 col x 8 contiguous k (coalesced scalar loads, single b128 write)
//   -> slot-group (5*col+kg)&7 uniform across wave = conflict-free.
// XCD-chunked 1-D grid, m innermost: blocks sharing a W-tile are co-resident per XCD.
__global__ __launch_bounds__(256, 3) void k_gateup(const float* __restrict__ x,
                                                   const float* __restrict__ wg_all,
                                                   const float* __restrict__ wu_all,
                                                   const int* __restrict__ offsets,
                                                   const int* __restrict__ token_ids,
                                                   __hip_bfloat16* __restrict__ hbuf) {
    unsigned b0 = blockIdx.x;
    unsigned w = (b0 & 7) * 512u + (b0 >> 3);     // XCD-chunked linearization (4096 blocks)
    int e  = w >> 8;
    int mi = w & 15;
    int ni = (w >> 4) & 15;
    int off = offsets[e];
    int n_e = offsets[e + 1] - off;
    int m0 = mi * 128;
    if (m0 >= n_e) return;
    int n0 = ni * 64;
    const float* wg = wg_all + (size_t)e * (D_DIM * F_DIM);
    const float* wu = wu_all + (size_t)e * (D_DIM * F_DIM);

    __shared__ unsigned short As[2][128 * 40];
    __shared__ unsigned short Bs[2][2][64 * 40];

    int tid = threadIdx.x;
    int wid = tid >> 6, lane = tid & 63;
    int q = lane >> 4, nl = lane & 15;
    int wr = wid >> 1, wc = wid & 1;

    // A staging: 2 threads/row, 16 fp32 each
    int arow = tid >> 1, acg = (tid & 1) * 16;
    int ag = m0 + arow;
    bool avalid = ag < n_e;
    const float* xrow = x + (size_t)(avalid ? token_ids[off + ag] : 0) * D_DIM;
    // B staging: thread -> col (tid&63), k-group (tid>>6)*8..+7
    int bcol = tid & 63;
    int bkg = (tid >> 6) * 8;

    f32x4 ra[4];
    float tg[8], tu[8];
    f32x4 accG[4][2], accU[4][2];
#pragma unroll
    for (int ms = 0; ms < 4; ++ms)
#pragma unroll
        for (int ns = 0; ns < 2; ++ns) {
            accG[ms][ns] = (f32x4){0.f, 0.f, 0.f, 0.f};
            accU[ms][ns] = (f32x4){0.f, 0.f, 0.f, 0.f};
        }

    auto loadG = [&](int k0) {
#pragma unroll
        for (int j = 0; j < 4; ++j)
            ra[j] = avalid ? *(const f32x4*)(xrow + k0 + acg + 4 * j) : (f32x4){0.f, 0.f, 0.f, 0.f};
        const float* pg = wg + (size_t)(k0 + bkg) * F_DIM + n0 + bcol;
        const float* pu = wu + (size_t)(k0 + bkg) * F_DIM + n0 + bcol;
#pragma unroll
        for (int i = 0; i < 8; ++i) {
            tg[i] = pg[(size_t)i * F_DIM];
            tu[i] = pu[(size_t)i * F_DIM];
        }
    };
    auto writeL = [&](int b) {
        unsigned short* a = &As[b][arow * 40 + acg];
        union { short8 v; unsigned u[4]; } w0, w1;
        w0.u[0] = pk2bf(ra[0].x, ra[0].y); w0.u[1] = pk2bf(ra[0].z, ra[0].w);
        w0.u[2] = pk2bf(ra[1].x, ra[1].y); w0.u[3] = pk2bf(ra[1].z, ra[1].w);
        w1.u[0] = pk2bf(ra[2].x, ra[2].y); w1.u[1] = pk2bf(ra[2].z, ra[2].w);
        w1.u[2] = pk2bf(ra[3].x, ra[3].y); w1.u[3] = pk2bf(ra[3].z, ra[3].w);
        *(short8*)a = w0.v; *(short8*)(a + 8) = w1.v;
        union { short8 v; unsigned u[4]; } g2, u2;
#pragma unroll
        for (int j = 0; j < 4; ++j) {
            g2.u[j] = pk2bf(tg[2 * j], tg[2 * j + 1]);
            u2.u[j] = pk2bf(tu[2 * j], tu[2 * j + 1]);
        }
        *(short8*)&Bs[b][0][bcol * 40 + bkg] = g2.v;
        *(short8*)&Bs[b][1][bcol * 40 + bkg] = u2.v;
    };
    auto compute = [&](int b) {
        short8 af[4];
#pragma unroll
        for (int ms = 0; ms < 4; ++ms)
            af[ms] = *(const short8*)&As[b][(wr * 64 + ms * 16 + nl) * 40 + q * 8];
#pragma unroll
        for (int ns = 0; ns < 2; ++ns) {
            int colb = (wc * 32 + ns * 16 + nl) * 40 + q * 8;
            short8 bg = *(const short8*)&Bs[b][0][colb];
            short8 bu = *(const short8*)&Bs[b][1][colb];
#pragma unroll
            for (int ms = 0; ms < 4; ++ms) {
                accG[ms][ns] = __builtin_amdgcn_mfma_f32_16x16x32_bf16(af[ms], bg, accG[ms][ns], 0, 0, 0);
                accU[ms][ns] = __builtin_amdgcn_mfma_f32_16x16x32_bf16(af[ms], bu, accU[ms][ns], 0, 0, 0);
            }
        }
    };

    loadG(0);
    writeL(0);
    __syncthreads();
    for (int t = 0; t < D_DIM / 32; ++t) {
        int b = t & 1;
        if (t < D_DIM / 32 - 1) loadG((t + 1) * 32);
        compute(b);
        if (t < D_DIM / 32 - 1) writeL(b ^ 1);
        __syncthreads();
    }

    // epilogue: silu(g)*u -> bf16 ; D layout: col=lane&15, row=(lane>>4)*4+j
#pragma unroll
    for (int ms = 0; ms < 4; ++ms)
#pragma unroll
        for (int j = 0; j < 4; ++j) {
            int g2 = m0 + wr * 64 + ms * 16 + q * 4 + j;
            if (g2 < n_e) {
                size_t hbase = (size_t)(off + g2) * F_DIM;
#pragma unroll
                for (int ns = 0; ns < 2; ++ns) {
                    float g = accG[ms][ns][j];
                    float u = accU[ms][ns][j];
                    float hv = (g / (1.f + __expf(-g))) * u;
                    hbuf[hbase + n0 + wc * 32 + ns * 16 + nl] = __float2bfloat16(hv);
                }
            }
        }
}

// ================= down grouped GEMM + weighted atomic combine =================
__global__ __launch_bounds__(256, 3) void k_down(const __hip_bfloat16* __restrict__ hbuf,
                                                 const float* __restrict__ wd_all,
                                                 const int* __restrict__ offsets,
                                                 const int* __restrict__ token_ids,
                                                 const float* __restrict__ slot_w,
                                                 float* __restrict__ y) {
    unsigned b0 = blockIdx.x;
    unsigned w = (b0 & 7) * 1024u + (b0 >> 3);    // XCD-chunked (8192 blocks)
    int e  = w >> 9;
    int mi = w & 15;
    int ni = (w >> 4) & 31;
    int off = offsets[e];
    int n_e = offsets[e + 1] - off;
    int m0 = mi * 128;
    if (m0 >= n_e) return;
    int n0 = ni * 64;
    const float* wd = wd_all + (size_t)e * (F_DIM * D_DIM);

    __shared__ unsigned short As[2][128 * 40];
    __shared__ unsigned short Bs[2][64 * 40];

    int tid = threadIdx.x;
    int wid = tid >> 6, lane = tid & 63;
    int q = lane >> 4, nl = lane & 15;
    int wr = wid >> 1, wc = wid & 1;

    int arow = tid >> 1, acg = (tid & 1) * 16;
    int ag = m0 + arow;
    bool avalid = ag < n_e;
    const unsigned short* hrow = (const unsigned short*)hbuf + (size_t)(off + (avalid ? ag : 0)) * F_DIM;
    int bcol = tid & 63;
    int bkg = (tid >> 6) * 8;

    short8 rh[2];
    float td[8];
    f32x4 acc[4][2];
#pragma unroll
    for (int ms = 0; ms < 4; ++ms)
#pragma unroll
        for (int ns = 0; ns < 2; ++ns) acc[ms][ns] = (f32x4){0.f, 0.f, 0.f, 0.f};

    auto loadG = [&](int k0) {
        if (avalid) {
            rh[0] = *(const short8*)(hrow + k0 + acg);
            rh[1] = *(const short8*)(hrow + k0 + acg + 8);
        } else {
            rh[0] = (short8){0, 0, 0, 0, 0, 0, 0, 0};
            rh[1] = (short8){0, 0, 0, 0, 0, 0, 0, 0};
        }
        const float* pd = wd + (size_t)(k0 + bkg) * D_DIM + n0 + bcol;
#pragma unroll
        for (int i = 0; i < 8; ++i) td[i] = pd[(size_t)i * D_DIM];
    };
    auto writeL = [&](int b) {
        unsigned short* a = &As[b][arow * 40 + acg];
        *(short8*)a = rh[0]; *(short8*)(a + 8) = rh[1];
        union { short8 v; unsigned u[4]; } d2;
#pragma unroll
        for (int j = 0; j < 4; ++j) d2.u[j] = pk2bf(td[2 * j], td[2 * j + 1]);
        *(short8*)&Bs[b][bcol * 40 + bkg] = d2.v;
    };
    auto compute = [&](int b) {
        short8 af[4];
#pragma unroll
        for (int ms = 0; ms < 4; ++ms)
            af[ms] = *(const short8*)&As[b][(wr * 64 + ms * 16 + nl) * 40 + q * 8];
#pragma unroll
        for (int ns = 0; ns < 2; ++ns) {
            short8 bd = *(const short8*)&Bs[b][(wc * 32 + ns * 16 + nl) * 40 + q * 8];
#pragma unroll
            for (int ms = 0; ms < 4; ++ms)
                acc[ms][ns] = __builtin_amdgcn_mfma_f32_16x16x32_bf16(af[ms], bd, acc[ms][ns], 0, 0, 0);
        }
    };

    loadG(0);
    writeL(0);
    __syncthreads();
    for (int t = 0; t < F_DIM / 32; ++t) {
        int b = t & 1;
        if (t < F_DIM / 32 - 1) loadG((t + 1) * 32);
        compute(b);
        if (t < F_DIM / 32 - 1) writeL(b ^ 1);
        __syncthreads();
    }

#pragma unroll
    for (int ms = 0; ms < 4; ++ms)
#pragma unroll
        for (int j = 0; j < 4; ++j) {
            int g2 = m0 + wr * 64 + ms * 16 + q * 4 + j;
            if (g2 < n_e) {
                float w2 = slot_w[off + g2];
                int t = token_ids[off + g2];
#pragma unroll
                for (int ns = 0; ns < 2; ++ns)
                    atomicAdd(&y[(size_t)t * D_DIM + n0 + wc * 32 + ns * 16 + nl], acc[ms][ns][j] * w2);
            }
        }
}

extern "C" void kernel_launch(void* const* d_in, const int* in_sizes, int n_in,
                              void* d_out, int out_size, void* d_ws, size_t ws_size,
                              hipStream_t stream) {
    const float* x      = (const float*)d_in[0];
    const float* w_gate = (const float*)d_in[1];
    const float* w_g    = (const float*)d_in[2];
    const float* w_u    = (const float*)d_in[3];
    const float* w_d    = (const float*)d_in[4];
    const float* bias   = (const float*)d_in[5];
    float* y = (float*)d_out;

    char* ws = (char*)d_ws;
    int*   counts    = (int*)(ws + 0);
    int*   offsets   = (int*)(ws + 64);
    int*   cursors   = (int*)(ws + 192);
    int*   topk_idx  = (int*)(ws + 256);
    float* topk_w    = (float*)(ws + 256 + 16384);
    int*   token_ids = (int*)(ws + 256 + 32768);
    float* slot_w    = (float*)(ws + 256 + 49152);
    __hip_bfloat16* hbuf = (__hip_bfloat16*)(ws + 66048);   // 4096*1024 bf16

    hipMemsetAsync(ws, 0, 256, stream);
    hipMemsetAsync(d_out, 0, (size_t)out_size * sizeof(float), stream);

    k_route<<<T_TOK, 64, 0, stream>>>(x, w_gate, bias, topk_idx, topk_w, counts);
    k_offsets<<<1, 64, 0, stream>>>(counts, offsets, cursors);
    k_scatter<<<(T_TOK * 2 + 255) / 256, 256, 0, stream>>>(topk_idx, topk_w, cursors, token_ids, slot_w);
    k_gateup<<<16 * 16 * E_NUM, 256, 0, stream>>>(x, w_g, w_u, offsets, token_ids, hbuf);
    k_down<<<16 * 32 * E_NUM, 256, 0, stream>>>(hbuf, w_d, offsets, token_ids, slot_w, y);
}

// Round 5
// 329.810 us; speedup vs baseline: 1.3248x; 1.3248x over previous
//
#include <hip/hip_runtime.h>
#include <hip/hip_bf16.h>

#define D_DIM 2048
#define F_DIM 1024
#define E_NUM 16
#define T_TOK 2048

typedef float f32x4 __attribute__((ext_vector_type(4)));
typedef short short8 __attribute__((ext_vector_type(8)));

__device__ inline unsigned pk2bf(float a, float b) {
    __hip_bfloat162 h2 = __float22bfloat162_rn(make_float2(a, b));
    union { __hip_bfloat162 h; unsigned u; } c; c.h = h2; return c.u;
}

// ---------------- routing: 1 wave per token ----------------
__global__ __launch_bounds__(64) void k_route(const float* __restrict__ x,
                                              const float* __restrict__ wg,
                                              const float* __restrict__ bias,
                                              int* __restrict__ topk_idx,
                                              float* __restrict__ topk_w,
                                              int* __restrict__ counts) {
    int t = blockIdx.x;
    int l = threadIdx.x;
    int e = l & 15, c = l >> 4;
    const float* xr = x + (size_t)t * D_DIM + c * (D_DIM / 4);
    const float* wr = wg + (size_t)(c * (D_DIM / 4)) * E_NUM + e;
    float acc = 0.f;
#pragma unroll 4
    for (int d = 0; d < D_DIM / 4; ++d) acc += xr[d] * wr[(size_t)d * E_NUM];
    acc += __shfl_xor(acc, 16);
    acc += __shfl_xor(acc, 32);
    float m = acc;
#pragma unroll
    for (int s = 1; s < 16; s <<= 1) m = fmaxf(m, __shfl_xor(m, s));
    float p = __expf(acc - m);
    float sum = p;
#pragma unroll
    for (int s = 1; s < 16; s <<= 1) sum += __shfl_xor(sum, s);
    p = p / sum + bias[e];
    float v1 = p; int i1 = e;
#pragma unroll
    for (int s = 1; s < 16; s <<= 1) {
        float ov = __shfl_xor(v1, s); int oi = __shfl_xor(i1, s);
        if (ov > v1 || (ov == v1 && oi < i1)) { v1 = ov; i1 = oi; }
    }
    float v2 = (e == i1) ? -1e30f : p; int i2 = e;
#pragma unroll
    for (int s = 1; s < 16; s <<= 1) {
        float ov = __shfl_xor(v2, s); int oi = __shfl_xor(i2, s);
        if (ov > v2 || (ov == v2 && oi < i2)) { v2 = ov; i2 = oi; }
    }
    if (l == 0) {
        float s2 = v1 + v2 + 1e-20f;
        topk_idx[2 * t] = i1; topk_idx[2 * t + 1] = i2;
        topk_w[2 * t] = v1 / s2; topk_w[2 * t + 1] = v2 / s2;
        atomicAdd(&counts[i1], 1);
        atomicAdd(&counts[i2], 1);
    }
}

__global__ void k_offsets(const int* __restrict__ counts, int* __restrict__ offsets,
                          int* __restrict__ cursors) {
    if (threadIdx.x == 0) {
        int run = 0;
        for (int e = 0; e < E_NUM; ++e) { offsets[e] = run; cursors[e] = run; run += counts[e]; }
        offsets[E_NUM] = run;
    }
}

__global__ void k_scatter(const int* __restrict__ topk_idx, const float* __restrict__ topk_w,
                          int* __restrict__ cursors, int* __restrict__ token_ids,
                          float* __restrict__ slot_w) {
    int i = blockIdx.x * blockDim.x + threadIdx.x;
    if (i >= T_TOK * 2) return;
    int e = topk_idx[i];
    int slot = atomicAdd(&cursors[e], 1);
    token_ids[slot] = i >> 1;
    slot_w[slot] = topk_w[i];
}

// ================= gate+up grouped GEMM =================
// tile 128(slots) x 64(F), BK=32, 4 waves (2x2), double-buffered (R3 structure).
// A LDS: [128 rows][32 k] bf16, stride 40 shorts (unchanged, conflict-free).
// B LDS: K-major [64 cols][32 k] bf16, stride 40, with k-group XOR swizzle:
//   element (col,k) lives at col*40 + (k ^ (((col>>3)&3)<<3)).
//   Write (4x b32/thread, R3 global float4 loads): banks = all 32, 2 lanes each = free.
//   Read (b128): start k-group q*8 -> 8*(q ^ ((col>>3)&3)); per-col permutation of q,
//   preserves the uniform slot-group distribution. Same involution both sides.
__global__ __launch_bounds__(256, 3) void k_gateup(const float* __restrict__ x,
                                                   const float* __restrict__ wg_all,
                                                   const float* __restrict__ wu_all,
                                                   const int* __restrict__ offsets,
                                                   const int* __restrict__ token_ids,
                                                   __hip_bfloat16* __restrict__ hbuf) {
    int e = blockIdx.z;
    int off = offsets[e];
    int n_e = offsets[e + 1] - off;
    int m0 = blockIdx.y * 128;
    if (m0 >= n_e) return;
    int n0 = blockIdx.x * 64;
    const float* wg = wg_all + (size_t)e * (D_DIM * F_DIM);
    const float* wu = wu_all + (size_t)e * (D_DIM * F_DIM);

    __shared__ unsigned short As[2][128 * 40];
    __shared__ unsigned short Bs[2][2][64 * 40];

    int tid = threadIdx.x;
    int wid = tid >> 6, lane = tid & 63;
    int q = lane >> 4, nl = lane & 15;
    int wr = wid >> 1, wc = wid & 1;

    // A staging: 2 threads/row, 16 fp32 each
    int arow = tid >> 1, acg = (tid & 1) * 16;
    int ag = m0 + arow;
    bool avalid = ag < n_e;
    const float* xrow = x + (size_t)(avalid ? token_ids[off + ag] : 0) * D_DIM;
    // B staging: thread -> k rows {bkr, bkr+1}, cols bcol..bcol+3 (float4 loads)
    int bkr = (tid >> 4) * 2;
    int bcol = (tid & 15) * 4;

    f32x4 ra[4], rg[2], ru[2];
    f32x4 accG[4][2], accU[4][2];
#pragma unroll
    for (int ms = 0; ms < 4; ++ms)
#pragma unroll
        for (int ns = 0; ns < 2; ++ns) {
            accG[ms][ns] = (f32x4){0.f, 0.f, 0.f, 0.f};
            accU[ms][ns] = (f32x4){0.f, 0.f, 0.f, 0.f};
        }

    auto loadG = [&](int k0) {
#pragma unroll
        for (int j = 0; j < 4; ++j)
            ra[j] = avalid ? *(const f32x4*)(xrow + k0 + acg + 4 * j) : (f32x4){0.f, 0.f, 0.f, 0.f};
        size_t o0 = (size_t)(k0 + bkr) * F_DIM + n0 + bcol;
        rg[0] = *(const f32x4*)(wg + o0);
        rg[1] = *(const f32x4*)(wg + o0 + F_DIM);
        ru[0] = *(const f32x4*)(wu + o0);
        ru[1] = *(const f32x4*)(wu + o0 + F_DIM);
    };
    auto writeL = [&](int b) {
        unsigned short* a = &As[b][arow * 40 + acg];
        union { short8 v; unsigned u[4]; } w0, w1;
        w0.u[0] = pk2bf(ra[0].x, ra[0].y); w0.u[1] = pk2bf(ra[0].z, ra[0].w);
        w0.u[2] = pk2bf(ra[1].x, ra[1].y); w0.u[3] = pk2bf(ra[1].z, ra[1].w);
        w1.u[0] = pk2bf(ra[2].x, ra[2].y); w1.u[1] = pk2bf(ra[2].z, ra[2].w);
        w1.u[2] = pk2bf(ra[3].x, ra[3].y); w1.u[3] = pk2bf(ra[3].z, ra[3].w);
        *(short8*)a = w0.v; *(short8*)(a + 8) = w1.v;
#pragma unroll
        for (int j = 0; j < 4; ++j) {
            int col = bcol + j;
            int kk = bkr ^ (((col >> 3) & 3) << 3);   // swizzled k-pair base
            *(unsigned*)&Bs[b][0][col * 40 + kk] = pk2bf(rg[0][j], rg[1][j]);
            *(unsigned*)&Bs[b][1][col * 40 + kk] = pk2bf(ru[0][j], ru[1][j]);
        }
    };
    auto compute = [&](int b) {
        short8 af[4];
#pragma unroll
        for (int ms = 0; ms < 4; ++ms)
            af[ms] = *(const short8*)&As[b][(wr * 64 + ms * 16 + nl) * 40 + q * 8];
#pragma unroll
        for (int ns = 0; ns < 2; ++ns) {
            int col = wc * 32 + ns * 16 + nl;
            int colb = col * 40 + 8 * (q ^ ((col >> 3) & 3));   // swizzled read
            short8 bg = *(const short8*)&Bs[b][0][colb];
            short8 bu = *(const short8*)&Bs[b][1][colb];
#pragma unroll
            for (int ms = 0; ms < 4; ++ms) {
                accG[ms][ns] = __builtin_amdgcn_mfma_f32_16x16x32_bf16(af[ms], bg, accG[ms][ns], 0, 0, 0);
                accU[ms][ns] = __builtin_amdgcn_mfma_f32_16x16x32_bf16(af[ms], bu, accU[ms][ns], 0, 0, 0);
            }
        }
    };

    loadG(0);
    writeL(0);
    __syncthreads();
    for (int t = 0; t < D_DIM / 32; ++t) {
        int b = t & 1;
        if (t < D_DIM / 32 - 1) loadG((t + 1) * 32);
        compute(b);
        if (t < D_DIM / 32 - 1) writeL(b ^ 1);
        __syncthreads();
    }

    // epilogue: silu(g)*u -> bf16 ; D layout: col=lane&15, row=(lane>>4)*4+j
#pragma unroll
    for (int ms = 0; ms < 4; ++ms)
#pragma unroll
        for (int j = 0; j < 4; ++j) {
            int g2 = m0 + wr * 64 + ms * 16 + q * 4 + j;
            if (g2 < n_e) {
                size_t hbase = (size_t)(off + g2) * F_DIM;
#pragma unroll
                for (int ns = 0; ns < 2; ++ns) {
                    float g = accG[ms][ns][j];
                    float u = accU[ms][ns][j];
                    float hv = (g / (1.f + __expf(-g))) * u;
                    hbuf[hbase + n0 + wc * 32 + ns * 16 + nl] = __float2bfloat16(hv);
                }
            }
        }
}

// ================= down grouped GEMM + weighted atomic combine =================
__global__ __launch_bounds__(256, 3) void k_down(const __hip_bfloat16* __restrict__ hbuf,
                                                 const float* __restrict__ wd_all,
                                                 const int* __restrict__ offsets,
                                                 const int* __restrict__ token_ids,
                                                 const float* __restrict__ slot_w,
                                                 float* __restrict__ y) {
    int e = blockIdx.z;
    int off = offsets[e];
    int n_e = offsets[e + 1] - off;
    int m0 = blockIdx.y * 128;
    if (m0 >= n_e) return;
    int n0 = blockIdx.x * 64;
    const float* wd = wd_all + (size_t)e * (F_DIM * D_DIM);

    __shared__ unsigned short As[2][128 * 40];
    __shared__ unsigned short Bs[2][64 * 40];

    int tid = threadIdx.x;
    int wid = tid >> 6, lane = tid & 63;
    int q = lane >> 4, nl = lane & 15;
    int wr = wid >> 1, wc = wid & 1;

    int arow = tid >> 1, acg = (tid & 1) * 16;
    int ag = m0 + arow;
    bool avalid = ag < n_e;
    const unsigned short* hrow = (const unsigned short*)hbuf + (size_t)(off + (avalid ? ag : 0)) * F_DIM;
    int bkr = (tid >> 4) * 2;
    int bcol = (tid & 15) * 4;

    short8 rh[2];
    f32x4 rd[2];
    f32x4 acc[4][2];
#pragma unroll
    for (int ms = 0; ms < 4; ++ms)
#pragma unroll
        for (int ns = 0; ns < 2; ++ns) acc[ms][ns] = (f32x4){0.f, 0.f, 0.f, 0.f};

    auto loadG = [&](int k0) {
        if (avalid) {
            rh[0] = *(const short8*)(hrow + k0 + acg);
            rh[1] = *(const short8*)(hrow + k0 + acg + 8);
        } else {
            rh[0] = (short8){0, 0, 0, 0, 0, 0, 0, 0};
            rh[1] = (short8){0, 0, 0, 0, 0, 0, 0, 0};
        }
        size_t o0 = (size_t)(k0 + bkr) * D_DIM + n0 + bcol;
        rd[0] = *(const f32x4*)(wd + o0);
        rd[1] = *(const f32x4*)(wd + o0 + D_DIM);
    };
    auto writeL = [&](int b) {
        unsigned short* a = &As[b][arow * 40 + acg];
        *(short8*)a = rh[0]; *(short8*)(a + 8) = rh[1];
#pragma unroll
        for (int j = 0; j < 4; ++j) {
            int col = bcol + j;
            int kk = bkr ^ (((col >> 3) & 3) << 3);   // swizzled k-pair base
            *(unsigned*)&Bs[b][col * 40 + kk] = pk2bf(rd[0][j], rd[1][j]);
        }
    };
    auto compute = [&](int b) {
        short8 af[4];
#pragma unroll
        for (int ms = 0; ms < 4; ++ms)
            af[ms] = *(const short8*)&As[b][(wr * 64 + ms * 16 + nl) * 40 + q * 8];
#pragma unroll
        for (int ns = 0; ns < 2; ++ns) {
            int col = wc * 32 + ns * 16 + nl;
            short8 bd = *(const short8*)&Bs[b][col * 40 + 8 * (q ^ ((col >> 3) & 3))];
#pragma unroll
            for (int ms = 0; ms < 4; ++ms)
                acc[ms][ns] = __builtin_amdgcn_mfma_f32_16x16x32_bf16(af[ms], bd, acc[ms][ns], 0, 0, 0);
        }
    };

    loadG(0);
    writeL(0);
    __syncthreads();
    for (int t = 0; t < F_DIM / 32; ++t) {
        int b = t & 1;
        if (t < F_DIM / 32 - 1) loadG((t + 1) * 32);
        compute(b);
        if (t < F_DIM / 32 - 1) writeL(b ^ 1);
        __syncthreads();
    }

#pragma unroll
    for (int ms = 0; ms < 4; ++ms)
#pragma unroll
        for (int j = 0; j < 4; ++j) {
            int g2 = m0 + wr * 64 + ms * 16 + q * 4 + j;
            if (g2 < n_e) {
                float w2 = slot_w[off + g2];
                int t = token_ids[off + g2];
#pragma unroll
                for (int ns = 0; ns < 2; ++ns)
                    atomicAdd(&y[(size_t)t * D_DIM + n0 + wc * 32 + ns * 16 + nl], acc[ms][ns][j] * w2);
            }
        }
}

extern "C" void kernel_launch(void* const* d_in, const int* in_sizes, int n_in,
                              void* d_out, int out_size, void* d_ws, size_t ws_size,
                              hipStream_t stream) {
    const float* x      = (const float*)d_in[0];
    const float* w_gate = (const float*)d_in[1];
    const float* w_g    = (const float*)d_in[2];
    const float* w_u    = (const float*)d_in[3];
    const float* w_d    = (const float*)d_in[4];
    const float* bias   = (const float*)d_in[5];
    float* y = (float*)d_out;

    char* ws = (char*)d_ws;
    int*   counts    = (int*)(ws + 0);
    int*   offsets   = (int*)(ws + 64);
    int*   cursors   = (int*)(ws + 192);
    int*   topk_idx  = (int*)(ws + 256);
    float* topk_w    = (float*)(ws + 256 + 16384);
    int*   token_ids = (int*)(ws + 256 + 32768);
    float* slot_w    = (float*)(ws + 256 + 49152);
    __hip_bfloat16* hbuf = (__hip_bfloat16*)(ws + 66048);   // 4096*1024 bf16

    hipMemsetAsync(ws, 0, 256, stream);
    hipMemsetAsync(d_out, 0, (size_t)out_size * sizeof(float), stream);

    k_route<<<T_TOK, 64, 0, stream>>>(x, w_gate, bias, topk_idx, topk_w, counts);
    k_offsets<<<1, 64, 0, stream>>>(counts, offsets, cursors);
    k_scatter<<<(T_TOK * 2 + 255) / 256, 256, 0, stream>>>(topk_idx, topk_w, cursors, token_ids, slot_w);
    k_gateup<<<dim3(F_DIM / 64, 16, E_NUM), 256, 0, stream>>>(x, w_g, w_u, offsets, token_ids, hbuf);
    k_down<<<dim3(D_DIM / 64, 16, E_NUM), 256, 0, stream>>>(hbuf, w_d, offsets, token_ids, slot_w, y);
}